// Round 6
// baseline (146.413 us; speedup 1.0000x reference)
//
#include <hip/hip_runtime.h>
#include <stdint.h>

#pragma clang fp contract(off)

#define NB 16
#define NC 80
#define P_TOT 17064
#define P4 (P_TOT / 4)
#define PRE_K 1000
#define POST_K 100

__device__ __forceinline__ float sigmoidf_(float x) {
  return 1.0f / (1.0f + expf(-x));
}

// Class-split decode: each 4-lane quad owns a 4-location group; lane t4 covers
// classes [20*t4, 20*t4+20). Exact per-class math, shfl-reduce with lower-label
// tie-break (== numpy argmax first-max semantics). Lane t4==0 writes.
__global__ __launch_bounds__(256) void decode_kernel(
    const float* __restrict__ cls0, const float* __restrict__ reg0, const float* __restrict__ ctr0,
    const float* __restrict__ cls1, const float* __restrict__ reg1, const float* __restrict__ ctr1,
    const float* __restrict__ cls2, const float* __restrict__ reg2, const float* __restrict__ ctr2,
    const float* __restrict__ cls3, const float* __restrict__ reg3, const float* __restrict__ ctr3,
    const float* __restrict__ cls4, const float* __restrict__ reg4, const float* __restrict__ ctr4,
    int* __restrict__ labels, float* __restrict__ boxes,
    unsigned long long* __restrict__ keys)
{
  int quad = blockIdx.x * 64 + (threadIdx.x >> 2);
  int t4 = threadIdx.x & 3;
  int n = blockIdx.y;
  if (quad >= P4) return;
  int p0 = quad * 4;
  int off, wsh, hw; float stride; const float *cls, *reg, *ctr;
  if (p0 < 12800)      { off = 0;     wsh = 7; hw = 12800; stride = 8.f;   cls = cls0; reg = reg0; ctr = ctr0; }
  else if (p0 < 16000) { off = 12800; wsh = 6; hw = 3200;  stride = 16.f;  cls = cls1; reg = reg1; ctr = ctr1; }
  else if (p0 < 16800) { off = 16000; wsh = 5; hw = 800;   stride = 32.f;  cls = cls2; reg = reg2; ctr = ctr2; }
  else if (p0 < 17008) { off = 16800; wsh = 4; hw = 208;   stride = 64.f;  cls = cls3; reg = reg3; ctr = ctr3; }
  else                 { off = 17008; wsh = 3; hw = 56;    stride = 128.f; cls = cls4; reg = reg4; ctr = ctr4; }
  int loc0 = p0 - off;
  int y = loc0 >> wsh;
  int x0 = loc0 & ((1 << wsh) - 1);
  float py = (float)y * stride + 0.5f * stride;

  float4 c4 = *reinterpret_cast<const float4*>(ctr + (size_t)n * hw + loc0);
  float sctr[4] = { sigmoidf_(c4.x), sigmoidf_(c4.y), sigmoidf_(c4.z), sigmoidf_(c4.w) };

  int c0 = t4 * 20;
  const float* cptr = cls + (size_t)n * NC * hw + (size_t)c0 * hw + loc0;
  float best[4] = { -1.f, -1.f, -1.f, -1.f };
  int bl[4] = { 0, 0, 0, 0 };
  #pragma unroll 5
  for (int k = 0; k < 20; ++k) {
    float4 cv = *reinterpret_cast<const float4*>(cptr + (size_t)k * hw);
    int c = c0 + k;
    float v;
    v = sqrtf(sigmoidf_(cv.x) * sctr[0]); if (v > best[0]) { best[0] = v; bl[0] = c; }
    v = sqrtf(sigmoidf_(cv.y) * sctr[1]); if (v > best[1]) { best[1] = v; bl[1] = c; }
    v = sqrtf(sigmoidf_(cv.z) * sctr[2]); if (v > best[2]) { best[2] = v; bl[2] = c; }
    v = sqrtf(sigmoidf_(cv.w) * sctr[3]); if (v > best[3]) { best[3] = v; bl[3] = c; }
  }

  // reduce across the quad (lanes t4=0..3): max, tie -> lower label
  #pragma unroll
  for (int e = 0; e < 4; ++e) {
    #pragma unroll
    for (int d = 1; d <= 2; d <<= 1) {
      float ob = __shfl_xor(best[e], d);
      int ol = __shfl_xor(bl[e], d);
      if (ob > best[e] || (ob == best[e] && ol < bl[e])) { best[e] = ob; bl[e] = ol; }
    }
  }
  if (t4 != 0) return;

  const float* rbase = reg + (size_t)n * 4 * hw + loc0;
  float4 rl = *reinterpret_cast<const float4*>(rbase);
  float4 rt = *reinterpret_cast<const float4*>(rbase + (size_t)hw);
  float4 rr = *reinterpret_cast<const float4*>(rbase + (size_t)2 * hw);
  float4 rb = *reinterpret_cast<const float4*>(rbase + (size_t)3 * hw);
  float dl[4] = { rl.x, rl.y, rl.z, rl.w };
  float dt[4] = { rt.x, rt.y, rt.z, rt.w };
  float dr[4] = { rr.x, rr.y, rr.z, rr.w };
  float db[4] = { rb.x, rb.y, rb.z, rb.w };

  size_t o0 = (size_t)n * P_TOT + p0;
  int4 bl4; int* blp = &bl4.x;
  unsigned long long kk[4];
  #pragma unroll
  for (int e = 0; e < 4; ++e) {
    float px = (float)(x0 + e) * stride + 0.5f * stride;
    float val = (best[e] > 0.05f) ? best[e] : 0.0f;
    float x1 = fminf(fmaxf(px - dl[e], 0.f), 1024.f);
    float y1 = fminf(fmaxf(py - dt[e], 0.f), 800.f);
    float x2 = fminf(fmaxf(px + dr[e], 0.f), 1024.f);
    float y2 = fminf(fmaxf(py + db[e], 0.f), 800.f);
    blp[e] = bl[e];
    *reinterpret_cast<float4*>(boxes + 4 * (o0 + e)) = make_float4(x1, y1, x2, y2);
    kk[e] = ((unsigned long long)__float_as_uint(val) << 32)
          | (unsigned long long)(0xFFFFFFFFu - (unsigned)(p0 + e));
  }
  *reinterpret_cast<int4*>(labels + o0) = bl4;
  ulonglong2 k01; k01.x = kk[0]; k01.y = kk[1];
  ulonglong2 k23; k23.x = kk[2]; k23.y = kk[3];
  *reinterpret_cast<ulonglong2*>(keys + o0) = k01;
  *reinterpret_cast<ulonglong2*>(keys + o0 + 2) = k23;
}

// Parallel histogram of key top-16 bits into ghist[n][65536] (pre-zeroed).
__global__ __launch_bounds__(256) void hist_kernel(
    const unsigned long long* __restrict__ keys, unsigned* __restrict__ ghist)
{
  int p = blockIdx.x * 256 + threadIdx.x;
  int n = blockIdx.y;
  if (p >= P_TOT) return;
  unsigned long long k = keys[(size_t)n * P_TOT + p];
  atomicAdd(&ghist[((size_t)n << 16) + (unsigned)(k >> 48)], 1u);
}

// Per batch (16 blocks x 1024): find threshold digit d (smallest top-16 value
// with suffix count >= 1000), compact all keys with top16 >= d (M in
// [1000, ~1300] << 2048), bitonic-sort 2048 desc, emit first 1000.
// Exactly the top-1000 keys in desc order (keys are unique).
__global__ __launch_bounds__(1024) void select_kernel(
    const unsigned long long* __restrict__ keys, const unsigned* __restrict__ ghist,
    unsigned long long* __restrict__ topkeys)
{
  int n = blockIdx.x;
  int tid = threadIdx.x;
  int lane = tid & 63;
  __shared__ unsigned A[1024];
  __shared__ unsigned long long skey[2048];
  __shared__ unsigned s_cnt, s_d;

  const unsigned* gh = ghist + ((size_t)n << 16);
  // strip of 64 bins per thread, cached in registers (statically indexed)
  unsigned bvs[64];
  const uint4* gh4 = reinterpret_cast<const uint4*>(gh) + (size_t)tid * 16;
  unsigned ssum = 0;
  #pragma unroll
  for (int q = 0; q < 16; ++q) {
    uint4 v = gh4[q];
    bvs[4*q+0] = v.x; bvs[4*q+1] = v.y; bvs[4*q+2] = v.z; bvs[4*q+3] = v.w;
    ssum += v.x + v.y + v.z + v.w;
  }
  A[tid] = ssum;
  if (tid == 0) s_cnt = 0;
  __syncthreads();
  // block suffix-scan: A[t] = sum strips t..1023
  for (int ofs = 1; ofs < 1024; ofs <<= 1) {
    unsigned v = A[tid];
    if (tid + ofs < 1024) v += A[tid + ofs];
    __syncthreads();
    A[tid] = v;
    __syncthreads();
  }
  {
    unsigned At = A[tid];
    unsigned An = (tid < 1023) ? A[tid + 1] : 0u;
    if (At >= PRE_K && An < PRE_K) {   // unique crossing strip (A monotone)
      unsigned cum = An;
      int d = tid * 64;
      bool done = false;
      #pragma unroll
      for (int b = 63; b >= 0; --b) {
        if (!done) {
          cum += bvs[b];
          if (cum >= PRE_K) { d = tid * 64 + b; done = true; }
        }
      }
      s_d = (unsigned)d;
    }
  }
  skey[tid] = 0ULL;
  skey[tid + 1024] = 0ULL;
  __syncthreads();
  unsigned dsel = s_d;

  const unsigned long long* bk = keys + (size_t)n * P_TOT;
  for (int p = tid; p < P_TOT; p += 1024) {
    unsigned long long k = bk[p];
    bool take = ((unsigned)(k >> 48) >= dsel);
    unsigned long long b = __ballot(take);
    if (b) {
      int leader = __ffsll(b) - 1;
      unsigned base = 0;
      if (lane == leader) base = atomicAdd(&s_cnt, (unsigned)__popcll(b));
      base = (unsigned)__shfl((int)base, leader);
      if (take) {
        unsigned pos = base + (unsigned)__popcll(b & ((1ull << lane) - 1ull));
        if (pos < 2048) skey[pos] = k;
      }
    }
  }
  __syncthreads();
  // bitonic sort 2048, descending; 2 elements per thread, disjoint pairs per step
  for (int k2 = 2; k2 <= 2048; k2 <<= 1) {
    for (int j = k2 >> 1; j > 0; j >>= 1) {
      #pragma unroll
      for (int e = 0; e < 2; ++e) {
        int idx = tid + e * 1024;
        int ixj = idx ^ j;
        if (ixj > idx) {
          unsigned long long a = skey[idx], bb = skey[ixj];
          bool sw = ((idx & k2) == 0) ? (a < bb) : (a > bb);
          if (sw) { skey[idx] = bb; skey[ixj] = a; }
        }
      }
      __syncthreads();
    }
  }
  if (tid < PRE_K) topkeys[(size_t)n * PRE_K + tid] = skey[tid];
}

__global__ __launch_bounds__(256) void gather_kernel(
    const unsigned long long* __restrict__ topkeys,
    const float* __restrict__ boxes, const int* __restrict__ labels,
    float* __restrict__ tboxes, float* __restrict__ tscores, int* __restrict__ tlabels)
{
  int i = blockIdx.x * 256 + threadIdx.x;
  if (i >= NB * PRE_K) return;
  int n = i / PRE_K;
  unsigned long long k = topkeys[i];
  unsigned idx = 0xFFFFFFFFu - (unsigned)(k & 0xFFFFFFFFu);
  float sc = __uint_as_float((unsigned)(k >> 32));
  size_t src = (size_t)n * P_TOT + idx;
  tscores[i] = sc;
  tlabels[i] = labels[src];
  tboxes[4*(size_t)i+0] = boxes[4*src+0];
  tboxes[4*(size_t)i+1] = boxes[4*src+1];
  tboxes[4*(size_t)i+2] = boxes[4*src+2];
  tboxes[4*(size_t)i+3] = boxes[4*src+3];
}

// COLUMN-major suppression, throughput-shaped.
// grid = (8 j-tiles, 16 i-words, NB).  Thread (jb*128+tid) computes the 64-bit
// word w of column j: bit b set iff i=w*64+b < j and IoU(offset boxes) > 0.6.
// No label test needed: the +label*4096 offset guarantees different-label pairs
// have zero intersection (coords < 4096/2).
__global__ __launch_bounds__(128) void iou_kernel(
    const float* __restrict__ tboxes, const int* __restrict__ tlabels,
    unsigned long long* __restrict__ colsupp)
{
  int jb = blockIdx.x, w = blockIdx.y, n = blockIdx.z;
  int tid = threadIdx.x;
  int j = jb * 128 + tid;
  bool jvalid = (j < PRE_K);

  if (w * 64 >= jb * 128 + 128) {
    if (jvalid) colsupp[((size_t)n * PRE_K + j) * 16 + w] = 0ULL;
    return;
  }

  __shared__ float4 sb[64];
  if (tid < 64) {
    int i = w * 64 + tid;
    float4 v = make_float4(0.f, 0.f, 0.f, 0.f);
    if (i < PRE_K) {
      const float* b = tboxes + ((size_t)n * PRE_K + i) * 4;
      float offv = (float)tlabels[(size_t)n * PRE_K + i] * 4096.0f;
      v = make_float4(b[0] + offv, b[1] + offv, b[2] + offv, b[3] + offv);
    }
    sb[tid] = v;
  }
  __syncthreads();

  float4 bj = make_float4(0.f, 0.f, 0.f, 0.f);
  if (jvalid) {
    const float* b = tboxes + ((size_t)n * PRE_K + j) * 4;
    float offv = (float)tlabels[(size_t)n * PRE_K + j] * 4096.0f;
    bj = make_float4(b[0] + offv, b[1] + offv, b[2] + offv, b[3] + offv);
  }
  float aj = (bj.z - bj.x) * (bj.w - bj.y);

  unsigned long long m = 0;
  int ibase = w * 64;
  #pragma unroll
  for (int b = 0; b < 64; ++b) {
    float4 bi = sb[b];
    float ai = (bi.z - bi.x) * (bi.w - bi.y);
    float lx = fmaxf(bi.x, bj.x), ly = fmaxf(bi.y, bj.y);
    float rx = fminf(bi.z, bj.z), ry = fminf(bi.w, bj.w);
    float iw = fmaxf(rx - lx, 0.f), ih = fmaxf(ry - ly, 0.f);
    float inter = iw * ih;
    float iou = inter / (ai + aj - inter + 1e-9f);
    if (iou > 0.6f && (ibase + b) < j) m |= (1ull << b);
  }
  if (jvalid) colsupp[((size_t)n * PRE_K + j) * 16 + w] = m;
}

// One wave per batch. Fixpoint greedy: per 64-chunk, K = candidates; repeat
// { S = K \ suppressed_by(K); kept |= S; K \= suppressed_by(kept) } until S=0.
// Provably equals the sequential greedy scan (cols only contain rows i<j).
// Cross-chunk words loaded per chunk (future words only), applied post-kept.
__global__ __launch_bounds__(64, 1) void greedy_kernel(
    const unsigned long long* __restrict__ colsupp, const float* __restrict__ tscores,
    unsigned long long* __restrict__ keepmask)
{
  int n = blockIdx.x;
  int l = threadIdx.x;
  const unsigned long long* C = colsupp + (size_t)n * PRE_K * 16;
  const float* sc = tscores + (size_t)n * PRE_K;

  // prefetch all diagonal words + scores (static-indexed -> registers)
  unsigned long long diag[16];
  float sval[16];
  #pragma unroll
  for (int k = 0; k < 16; ++k) {
    int j = k * 64 + l;
    diag[k] = (j < PRE_K) ? C[(size_t)j * 16 + k] : 0ULL;
    sval[k] = (j < PRE_K) ? sc[j] : 0.f;
  }

  unsigned removedbits = 0;  // bit k: column k*64+l removed
  #pragma unroll
  for (int c = 0; c < 16; ++c) {
    // issue future-chunk cross words early; consumed after the fixpoint
    unsigned long long X[16];
    #pragma unroll
    for (int w = 0; w < 16; ++w) {
      X[w] = 0ULL;
      if (w > c) {
        int j = w * 64 + l;
        if (j < PRE_K) X[w] = C[(size_t)j * 16 + c];
      }
    }
    unsigned long long sp = __ballot(sval[c] > 0.f);
    unsigned long long inc = __ballot(((removedbits >> c) & 1u) != 0u);
    unsigned long long K = sp & ~inc;
    unsigned long long col = diag[c];
    unsigned long long kept = 0;
    for (int it = 0; it < 64; ++it) {
      unsigned long long Bsupp = __ballot((col & K) != 0ULL);
      unsigned long long Snew = K & ~Bsupp & ~kept;
      if (Snew == 0ULL) break;
      kept |= Snew;
      unsigned long long Bd = __ballot((col & kept) != 0ULL);
      K &= ~Bd;
    }
    if ((col & kept) != 0ULL) removedbits |= (1u << c);
    #pragma unroll
    for (int w = 0; w < 16; ++w)
      if (w > c && (X[w] & kept) != 0ULL) removedbits |= (1u << w);
  }
  #pragma unroll
  for (int k = 0; k < 16; ++k) {
    unsigned long long w = __ballot(((removedbits >> k) & 1u) != 0u);
    if (l == 0) keepmask[(size_t)n * 16 + k] = w;
  }
}

__global__ __launch_bounds__(1024) void finalize_kernel(
    const unsigned long long* __restrict__ keepmask, const float* __restrict__ tscores,
    const float* __restrict__ tboxes, const int* __restrict__ tlabels,
    float* __restrict__ out)
{
  int n = blockIdx.x;
  int tid = threadIdx.x;
  __shared__ unsigned sk[1024];
  __shared__ unsigned sz[1024];
  bool inr = (tid < PRE_K);
  bool keep = false; float sc = 0.f;
  if (inr) {
    unsigned long long w = keepmask[(size_t)n * 16 + (tid >> 6)];
    bool rem = (w >> (tid & 63)) & 1ull;
    sc = tscores[(size_t)n * PRE_K + tid];
    keep = (!rem) && (sc > 0.f);
  }
  sk[tid] = keep ? 1u : 0u;
  sz[tid] = (inr && !keep) ? 1u : 0u;
  __syncthreads();
  for (int ofs = 1; ofs < 1024; ofs <<= 1) {
    unsigned a = (tid >= ofs) ? sk[tid - ofs] : 0;
    unsigned b = (tid >= ofs) ? sz[tid - ofs] : 0;
    __syncthreads();
    sk[tid] += a; sz[tid] += b;
    __syncthreads();
  }
  int nk = (int)sk[1023];
  int slot = -1;
  if (inr) {
    if (keep) {
      int r = (int)sk[tid] - 1;
      if (r < POST_K) slot = r;
    } else {
      int r = nk + (int)sz[tid] - 1;
      if (r < POST_K) slot = r;
    }
  }
  if (slot >= 0) {
    size_t src = (size_t)n * PRE_K + tid;
    size_t ob = ((size_t)n * POST_K + slot) * 4;
    out[ob+0] = tboxes[4*src+0];
    out[ob+1] = tboxes[4*src+1];
    out[ob+2] = tboxes[4*src+2];
    out[ob+3] = tboxes[4*src+3];
    out[(size_t)NB*POST_K*4 + (size_t)n*POST_K + slot] = keep ? sc : 0.0f;
    out[(size_t)NB*POST_K*5 + (size_t)n*POST_K + slot] = (float)tlabels[src];
  }
}

extern "C" void kernel_launch(void* const* d_in, const int* in_sizes, int n_in,
                              void* d_out, int out_size, void* d_ws, size_t ws_size,
                              hipStream_t stream) {
  char* w = (char*)d_ws;
  auto carve = [&](size_t bytes) { char* p = w; w += (bytes + 255) & ~(size_t)255; return p; };
  int* labels   = (int*)carve((size_t)NB * P_TOT * 4);
  float* boxes  = (float*)carve((size_t)NB * P_TOT * 16);
  unsigned long long* keys    = (unsigned long long*)carve((size_t)NB * P_TOT * 8);
  // ghist (16 x 65536 u32 = 4 MB) aliases colsupp (2 MB): ghist's lifetime ends
  // at select_kernel (dispatch 4); colsupp is first written by iou (dispatch 6).
  char* shared_scratch = carve((size_t)NB * 65536 * 4);
  unsigned* ghist = (unsigned*)shared_scratch;
  unsigned long long* colsupp = (unsigned long long*)shared_scratch;
  unsigned long long* topkeys = (unsigned long long*)carve((size_t)NB * PRE_K * 8);
  float* tboxes  = (float*)carve((size_t)NB * PRE_K * 16);
  float* tscores = (float*)carve((size_t)NB * PRE_K * 4);
  int* tlabels   = (int*)carve((size_t)NB * PRE_K * 4);
  unsigned long long* keepmask = (unsigned long long*)carve((size_t)NB * 16 * 8);

  const float* cls0 = (const float*)d_in[0];
  const float* reg0 = (const float*)d_in[1];
  const float* ctr0 = (const float*)d_in[2];
  const float* cls1 = (const float*)d_in[3];
  const float* reg1 = (const float*)d_in[4];
  const float* ctr1 = (const float*)d_in[5];
  const float* cls2 = (const float*)d_in[6];
  const float* reg2 = (const float*)d_in[7];
  const float* ctr2 = (const float*)d_in[8];
  const float* cls3 = (const float*)d_in[9];
  const float* reg3 = (const float*)d_in[10];
  const float* ctr3 = (const float*)d_in[11];
  const float* cls4 = (const float*)d_in[12];
  const float* reg4 = (const float*)d_in[13];
  const float* ctr4 = (const float*)d_in[14];

  hipMemsetAsync(ghist, 0, (size_t)NB * 65536 * 4, stream);
  dim3 dg((P4 + 63) / 64, NB);
  decode_kernel<<<dg, 256, 0, stream>>>(cls0, reg0, ctr0, cls1, reg1, ctr1,
                                        cls2, reg2, ctr2, cls3, reg3, ctr3,
                                        cls4, reg4, ctr4,
                                        labels, boxes, keys);
  dim3 gh((P_TOT + 255) / 256, NB);
  hist_kernel<<<gh, 256, 0, stream>>>(keys, ghist);
  select_kernel<<<NB, 1024, 0, stream>>>(keys, ghist, topkeys);
  gather_kernel<<<(NB * PRE_K + 255) / 256, 256, 0, stream>>>(topkeys, boxes, labels,
                                                              tboxes, tscores, tlabels);
  dim3 gi(8, 16, NB);
  iou_kernel<<<gi, 128, 0, stream>>>(tboxes, tlabels, colsupp);
  greedy_kernel<<<NB, 64, 0, stream>>>(colsupp, tscores, keepmask);
  finalize_kernel<<<NB, 1024, 0, stream>>>(keepmask, tscores, tboxes, tlabels, (float*)d_out);
}

// Round 7
// 145.868 us; speedup vs baseline: 1.0037x; 1.0037x over previous
//
#include <hip/hip_runtime.h>
#include <stdint.h>

#pragma clang fp contract(off)

#define NB 16
#define NC 80
#define P_TOT 17064
#define P4 (P_TOT / 4)
#define PRE_K 1000
#define POST_K 100

__device__ __forceinline__ float sigmoidf_(float x) {
  return 1.0f / (1.0f + expf(-x));
}

// Class-split decode: each 8-lane group owns a 4-location group; lane t8 covers
// classes [10*t8, 10*t8+10), fully unrolled (10 loads in flight). Exact per-class
// math; shfl-reduce with lower-label tie-break (numpy argmax first-max semantics;
// chunk ranges ascend with t8 so equal->lower-label is exact). Lane t8==0 writes.
__global__ __launch_bounds__(256) void decode_kernel(
    const float* __restrict__ cls0, const float* __restrict__ reg0, const float* __restrict__ ctr0,
    const float* __restrict__ cls1, const float* __restrict__ reg1, const float* __restrict__ ctr1,
    const float* __restrict__ cls2, const float* __restrict__ reg2, const float* __restrict__ ctr2,
    const float* __restrict__ cls3, const float* __restrict__ reg3, const float* __restrict__ ctr3,
    const float* __restrict__ cls4, const float* __restrict__ reg4, const float* __restrict__ ctr4,
    int* __restrict__ labels, float* __restrict__ boxes,
    unsigned long long* __restrict__ keys)
{
  int quad = blockIdx.x * 32 + (threadIdx.x >> 3);
  int t8 = threadIdx.x & 7;
  int n = blockIdx.y;
  if (quad >= P4) return;
  int p0 = quad * 4;
  int off, wsh, hw; float stride; const float *cls, *reg, *ctr;
  if (p0 < 12800)      { off = 0;     wsh = 7; hw = 12800; stride = 8.f;   cls = cls0; reg = reg0; ctr = ctr0; }
  else if (p0 < 16000) { off = 12800; wsh = 6; hw = 3200;  stride = 16.f;  cls = cls1; reg = reg1; ctr = ctr1; }
  else if (p0 < 16800) { off = 16000; wsh = 5; hw = 800;   stride = 32.f;  cls = cls2; reg = reg2; ctr = ctr2; }
  else if (p0 < 17008) { off = 16800; wsh = 4; hw = 208;   stride = 64.f;  cls = cls3; reg = reg3; ctr = ctr3; }
  else                 { off = 17008; wsh = 3; hw = 56;    stride = 128.f; cls = cls4; reg = reg4; ctr = ctr4; }
  int loc0 = p0 - off;
  int y = loc0 >> wsh;
  int x0 = loc0 & ((1 << wsh) - 1);
  float py = (float)y * stride + 0.5f * stride;

  float4 c4 = *reinterpret_cast<const float4*>(ctr + (size_t)n * hw + loc0);
  float sctr[4] = { sigmoidf_(c4.x), sigmoidf_(c4.y), sigmoidf_(c4.z), sigmoidf_(c4.w) };

  int c0 = t8 * 10;
  const float* cptr = cls + (size_t)n * NC * hw + (size_t)c0 * hw + loc0;
  float best[4] = { -1.f, -1.f, -1.f, -1.f };
  int bl[4] = { 0, 0, 0, 0 };
  #pragma unroll
  for (int k = 0; k < 10; ++k) {
    float4 cv = *reinterpret_cast<const float4*>(cptr + (size_t)k * hw);
    int c = c0 + k;
    float v;
    v = sqrtf(sigmoidf_(cv.x) * sctr[0]); if (v > best[0]) { best[0] = v; bl[0] = c; }
    v = sqrtf(sigmoidf_(cv.y) * sctr[1]); if (v > best[1]) { best[1] = v; bl[1] = c; }
    v = sqrtf(sigmoidf_(cv.z) * sctr[2]); if (v > best[2]) { best[2] = v; bl[2] = c; }
    v = sqrtf(sigmoidf_(cv.w) * sctr[3]); if (v > best[3]) { best[3] = v; bl[3] = c; }
  }

  // reduce across the 8-lane group: max, tie -> lower label
  #pragma unroll
  for (int e = 0; e < 4; ++e) {
    #pragma unroll
    for (int d = 1; d <= 4; d <<= 1) {
      float ob = __shfl_xor(best[e], d);
      int ol = __shfl_xor(bl[e], d);
      if (ob > best[e] || (ob == best[e] && ol < bl[e])) { best[e] = ob; bl[e] = ol; }
    }
  }
  if (t8 != 0) return;

  const float* rbase = reg + (size_t)n * 4 * hw + loc0;
  float4 rl = *reinterpret_cast<const float4*>(rbase);
  float4 rt = *reinterpret_cast<const float4*>(rbase + (size_t)hw);
  float4 rr = *reinterpret_cast<const float4*>(rbase + (size_t)2 * hw);
  float4 rb = *reinterpret_cast<const float4*>(rbase + (size_t)3 * hw);
  float dl[4] = { rl.x, rl.y, rl.z, rl.w };
  float dt[4] = { rt.x, rt.y, rt.z, rt.w };
  float dr[4] = { rr.x, rr.y, rr.z, rr.w };
  float db[4] = { rb.x, rb.y, rb.z, rb.w };

  size_t o0 = (size_t)n * P_TOT + p0;
  int4 bl4; int* blp = &bl4.x;
  unsigned long long kk[4];
  #pragma unroll
  for (int e = 0; e < 4; ++e) {
    float px = (float)(x0 + e) * stride + 0.5f * stride;
    float val = (best[e] > 0.05f) ? best[e] : 0.0f;
    float x1 = fminf(fmaxf(px - dl[e], 0.f), 1024.f);
    float y1 = fminf(fmaxf(py - dt[e], 0.f), 800.f);
    float x2 = fminf(fmaxf(px + dr[e], 0.f), 1024.f);
    float y2 = fminf(fmaxf(py + db[e], 0.f), 800.f);
    blp[e] = bl[e];
    *reinterpret_cast<float4*>(boxes + 4 * (o0 + e)) = make_float4(x1, y1, x2, y2);
    kk[e] = ((unsigned long long)__float_as_uint(val) << 32)
          | (unsigned long long)(0xFFFFFFFFu - (unsigned)(p0 + e));
  }
  *reinterpret_cast<int4*>(labels + o0) = bl4;
  ulonglong2 k01; k01.x = kk[0]; k01.y = kk[1];
  ulonglong2 k23; k23.x = kk[2]; k23.y = kk[3];
  *reinterpret_cast<ulonglong2*>(keys + o0) = k01;
  *reinterpret_cast<ulonglong2*>(keys + o0 + 2) = k23;
}

// Parallel histogram of key top-16 bits into ghist[n][65536] (pre-zeroed).
__global__ __launch_bounds__(256) void hist_kernel(
    const unsigned long long* __restrict__ keys, unsigned* __restrict__ ghist)
{
  int p = blockIdx.x * 256 + threadIdx.x;
  int n = blockIdx.y;
  if (p >= P_TOT) return;
  unsigned long long k = keys[(size_t)n * P_TOT + p];
  atomicAdd(&ghist[((size_t)n << 16) + (unsigned)(k >> 48)], 1u);
}

// Phase B (per batch): find threshold digit dsel (smallest top-16 value with
// suffix count >= 1000). Then overwrite ghist[h] with the BASE offset (count of
// keys in bins > h) for non-empty bins h >= dsel (all bases < 1000 by
// construction), and zero the 2048-slot staging buffer.
__global__ __launch_bounds__(1024) void selB_kernel(
    unsigned* __restrict__ ghist, unsigned* __restrict__ dsel_arr,
    unsigned long long* __restrict__ stage)
{
  int n = blockIdx.x;
  int tid = threadIdx.x;
  __shared__ unsigned A[1024];
  __shared__ unsigned s_d;

  unsigned* gh = ghist + ((size_t)n << 16);
  unsigned bvs[64];
  const uint4* gh4 = reinterpret_cast<const uint4*>(gh) + (size_t)tid * 16;
  unsigned ssum = 0;
  #pragma unroll
  for (int q = 0; q < 16; ++q) {
    uint4 v = gh4[q];
    bvs[4*q+0] = v.x; bvs[4*q+1] = v.y; bvs[4*q+2] = v.z; bvs[4*q+3] = v.w;
    ssum += v.x + v.y + v.z + v.w;
  }
  A[tid] = ssum;
  __syncthreads();
  // block suffix-scan: A[t] = sum strips t..1023
  for (int ofs = 1; ofs < 1024; ofs <<= 1) {
    unsigned v = A[tid];
    if (tid + ofs < 1024) v += A[tid + ofs];
    __syncthreads();
    A[tid] = v;
    __syncthreads();
  }
  unsigned An = (tid < 1023) ? A[tid + 1] : 0u;
  {
    unsigned At = A[tid];
    if (At >= PRE_K && An < PRE_K) {   // unique crossing strip (A monotone)
      unsigned cum = An;
      int d = tid * 64;
      bool done = false;
      #pragma unroll
      for (int b = 63; b >= 0; --b) {
        if (!done) {
          cum += bvs[b];
          if (cum >= PRE_K) { d = tid * 64 + b; done = true; }
        }
      }
      s_d = (unsigned)d;
      if (tid == 0 || true) dsel_arr[n] = (unsigned)d;
    }
  }
  __syncthreads();
  unsigned dsel = s_d;
  // write bases for non-empty bins >= dsel (bases < 1000, fit low 16 bits)
  {
    unsigned cum = An;
    #pragma unroll
    for (int b = 63; b >= 0; --b) {
      unsigned h = (unsigned)(tid * 64 + b);
      if (h >= dsel && bvs[b] != 0u) gh[h] = cum;
      cum += bvs[b];
    }
  }
  // zero staging slots
  stage[(size_t)n * 2048 + tid] = 0ULL;
  stage[(size_t)n * 2048 + tid + 1024] = 0ULL;
}

// Phase C: parallel bucket scatter. Each candidate key (top16 >= dsel) takes
// slot = base[h] + within-bin-count (atomic). Slots unique, bin-ordered.
__global__ __launch_bounds__(256) void scatter_kernel(
    const unsigned long long* __restrict__ keys, unsigned* __restrict__ ghist,
    const unsigned* __restrict__ dsel_arr, unsigned long long* __restrict__ stage)
{
  int p = blockIdx.x * 256 + threadIdx.x;
  int n = blockIdx.y;
  if (p >= P_TOT) return;
  unsigned long long k = keys[(size_t)n * P_TOT + p];
  unsigned h = (unsigned)(k >> 48);
  if (h < dsel_arr[n]) return;
  unsigned old = atomicAdd(&ghist[((size_t)n << 16) + h], 0x10000u);
  unsigned slot = (old & 0xFFFFu) + (old >> 16);
  if (slot < 2048) stage[(size_t)n * 2048 + slot] = k;
}

// Phase D (per batch): bitonic-sort the 2048 staged keys desc (zeros pad the
// tail), emit the first 1000 — exactly the top-1000 keys in desc order.
__global__ __launch_bounds__(1024) void sortD_kernel(
    const unsigned long long* __restrict__ stage, unsigned long long* __restrict__ topkeys)
{
  int n = blockIdx.x;
  int tid = threadIdx.x;
  __shared__ unsigned long long skey[2048];
  skey[tid] = stage[(size_t)n * 2048 + tid];
  skey[tid + 1024] = stage[(size_t)n * 2048 + tid + 1024];
  __syncthreads();
  for (int k2 = 2; k2 <= 2048; k2 <<= 1) {
    for (int j = k2 >> 1; j > 0; j >>= 1) {
      #pragma unroll
      for (int e = 0; e < 2; ++e) {
        int idx = tid + e * 1024;
        int ixj = idx ^ j;
        if (ixj > idx) {
          unsigned long long a = skey[idx], bb = skey[ixj];
          bool sw = ((idx & k2) == 0) ? (a < bb) : (a > bb);
          if (sw) { skey[idx] = bb; skey[ixj] = a; }
        }
      }
      __syncthreads();
    }
  }
  if (tid < PRE_K) topkeys[(size_t)n * PRE_K + tid] = skey[tid];
}

__global__ __launch_bounds__(256) void gather_kernel(
    const unsigned long long* __restrict__ topkeys,
    const float* __restrict__ boxes, const int* __restrict__ labels,
    float* __restrict__ tboxes, float* __restrict__ tscores, int* __restrict__ tlabels)
{
  int i = blockIdx.x * 256 + threadIdx.x;
  if (i >= NB * PRE_K) return;
  int n = i / PRE_K;
  unsigned long long k = topkeys[i];
  unsigned idx = 0xFFFFFFFFu - (unsigned)(k & 0xFFFFFFFFu);
  float sc = __uint_as_float((unsigned)(k >> 32));
  size_t src = (size_t)n * P_TOT + idx;
  tscores[i] = sc;
  tlabels[i] = labels[src];
  tboxes[4*(size_t)i+0] = boxes[4*src+0];
  tboxes[4*(size_t)i+1] = boxes[4*src+1];
  tboxes[4*(size_t)i+2] = boxes[4*src+2];
  tboxes[4*(size_t)i+3] = boxes[4*src+3];
}

// COLUMN-major suppression, throughput-shaped.
// grid = (8 j-tiles, 16 i-words, NB).  Thread (jb*128+tid) computes the 64-bit
// word w of column j: bit b set iff i=w*64+b < j and IoU(offset boxes) > 0.6.
// No label test needed: the +label*4096 offset guarantees different-label pairs
// have zero intersection (coords < 4096/2).
__global__ __launch_bounds__(128) void iou_kernel(
    const float* __restrict__ tboxes, const int* __restrict__ tlabels,
    unsigned long long* __restrict__ colsupp)
{
  int jb = blockIdx.x, w = blockIdx.y, n = blockIdx.z;
  int tid = threadIdx.x;
  int j = jb * 128 + tid;
  bool jvalid = (j < PRE_K);

  if (w * 64 >= jb * 128 + 128) {
    if (jvalid) colsupp[((size_t)n * PRE_K + j) * 16 + w] = 0ULL;
    return;
  }

  __shared__ float4 sb[64];
  if (tid < 64) {
    int i = w * 64 + tid;
    float4 v = make_float4(0.f, 0.f, 0.f, 0.f);
    if (i < PRE_K) {
      const float* b = tboxes + ((size_t)n * PRE_K + i) * 4;
      float offv = (float)tlabels[(size_t)n * PRE_K + i] * 4096.0f;
      v = make_float4(b[0] + offv, b[1] + offv, b[2] + offv, b[3] + offv);
    }
    sb[tid] = v;
  }
  __syncthreads();

  float4 bj = make_float4(0.f, 0.f, 0.f, 0.f);
  if (jvalid) {
    const float* b = tboxes + ((size_t)n * PRE_K + j) * 4;
    float offv = (float)tlabels[(size_t)n * PRE_K + j] * 4096.0f;
    bj = make_float4(b[0] + offv, b[1] + offv, b[2] + offv, b[3] + offv);
  }
  float aj = (bj.z - bj.x) * (bj.w - bj.y);

  unsigned long long m = 0;
  int ibase = w * 64;
  #pragma unroll
  for (int b = 0; b < 64; ++b) {
    float4 bi = sb[b];
    float ai = (bi.z - bi.x) * (bi.w - bi.y);
    float lx = fmaxf(bi.x, bj.x), ly = fmaxf(bi.y, bj.y);
    float rx = fminf(bi.z, bj.z), ry = fminf(bi.w, bj.w);
    float iw = fmaxf(rx - lx, 0.f), ih = fmaxf(ry - ly, 0.f);
    float inter = iw * ih;
    float iou = inter / (ai + aj - inter + 1e-9f);
    if (iou > 0.6f && (ibase + b) < j) m |= (1ull << b);
  }
  if (jvalid) colsupp[((size_t)n * PRE_K + j) * 16 + w] = m;
}

// One wave per batch. Fixpoint greedy: per 64-chunk, K = candidates; repeat
// { S = K \ suppressed_by(K); kept |= S; K \= suppressed_by(kept) } until S=0.
// Provably equals the sequential greedy scan (cols only contain rows i<j).
// Cross-chunk words loaded per chunk (future words only), applied post-kept.
__global__ __launch_bounds__(64, 1) void greedy_kernel(
    const unsigned long long* __restrict__ colsupp, const float* __restrict__ tscores,
    unsigned long long* __restrict__ keepmask)
{
  int n = blockIdx.x;
  int l = threadIdx.x;
  const unsigned long long* C = colsupp + (size_t)n * PRE_K * 16;
  const float* sc = tscores + (size_t)n * PRE_K;

  unsigned long long diag[16];
  float sval[16];
  #pragma unroll
  for (int k = 0; k < 16; ++k) {
    int j = k * 64 + l;
    diag[k] = (j < PRE_K) ? C[(size_t)j * 16 + k] : 0ULL;
    sval[k] = (j < PRE_K) ? sc[j] : 0.f;
  }

  unsigned removedbits = 0;  // bit k: column k*64+l removed
  #pragma unroll
  for (int c = 0; c < 16; ++c) {
    unsigned long long X[16];
    #pragma unroll
    for (int w = 0; w < 16; ++w) {
      X[w] = 0ULL;
      if (w > c) {
        int j = w * 64 + l;
        if (j < PRE_K) X[w] = C[(size_t)j * 16 + c];
      }
    }
    unsigned long long sp = __ballot(sval[c] > 0.f);
    unsigned long long inc = __ballot(((removedbits >> c) & 1u) != 0u);
    unsigned long long K = sp & ~inc;
    unsigned long long col = diag[c];
    unsigned long long kept = 0;
    for (int it = 0; it < 64; ++it) {
      unsigned long long Bsupp = __ballot((col & K) != 0ULL);
      unsigned long long Snew = K & ~Bsupp & ~kept;
      if (Snew == 0ULL) break;
      kept |= Snew;
      unsigned long long Bd = __ballot((col & kept) != 0ULL);
      K &= ~Bd;
    }
    if ((col & kept) != 0ULL) removedbits |= (1u << c);
    #pragma unroll
    for (int w = 0; w < 16; ++w)
      if (w > c && (X[w] & kept) != 0ULL) removedbits |= (1u << w);
  }
  #pragma unroll
  for (int k = 0; k < 16; ++k) {
    unsigned long long w = __ballot(((removedbits >> k) & 1u) != 0u);
    if (l == 0) keepmask[(size_t)n * 16 + k] = w;
  }
}

__global__ __launch_bounds__(1024) void finalize_kernel(
    const unsigned long long* __restrict__ keepmask, const float* __restrict__ tscores,
    const float* __restrict__ tboxes, const int* __restrict__ tlabels,
    float* __restrict__ out)
{
  int n = blockIdx.x;
  int tid = threadIdx.x;
  __shared__ unsigned sk[1024];
  __shared__ unsigned sz[1024];
  bool inr = (tid < PRE_K);
  bool keep = false; float sc = 0.f;
  if (inr) {
    unsigned long long w = keepmask[(size_t)n * 16 + (tid >> 6)];
    bool rem = (w >> (tid & 63)) & 1ull;
    sc = tscores[(size_t)n * PRE_K + tid];
    keep = (!rem) && (sc > 0.f);
  }
  sk[tid] = keep ? 1u : 0u;
  sz[tid] = (inr && !keep) ? 1u : 0u;
  __syncthreads();
  for (int ofs = 1; ofs < 1024; ofs <<= 1) {
    unsigned a = (tid >= ofs) ? sk[tid - ofs] : 0;
    unsigned b = (tid >= ofs) ? sz[tid - ofs] : 0;
    __syncthreads();
    sk[tid] += a; sz[tid] += b;
    __syncthreads();
  }
  int nk = (int)sk[1023];
  int slot = -1;
  if (inr) {
    if (keep) {
      int r = (int)sk[tid] - 1;
      if (r < POST_K) slot = r;
    } else {
      int r = nk + (int)sz[tid] - 1;
      if (r < POST_K) slot = r;
    }
  }
  if (slot >= 0) {
    size_t src = (size_t)n * PRE_K + tid;
    size_t ob = ((size_t)n * POST_K + slot) * 4;
    out[ob+0] = tboxes[4*src+0];
    out[ob+1] = tboxes[4*src+1];
    out[ob+2] = tboxes[4*src+2];
    out[ob+3] = tboxes[4*src+3];
    out[(size_t)NB*POST_K*4 + (size_t)n*POST_K + slot] = keep ? sc : 0.0f;
    out[(size_t)NB*POST_K*5 + (size_t)n*POST_K + slot] = (float)tlabels[src];
  }
}

extern "C" void kernel_launch(void* const* d_in, const int* in_sizes, int n_in,
                              void* d_out, int out_size, void* d_ws, size_t ws_size,
                              hipStream_t stream) {
  char* w = (char*)d_ws;
  auto carve = [&](size_t bytes) { char* p = w; w += (bytes + 255) & ~(size_t)255; return p; };
  int* labels   = (int*)carve((size_t)NB * P_TOT * 4);
  float* boxes  = (float*)carve((size_t)NB * P_TOT * 16);
  unsigned long long* keys    = (unsigned long long*)carve((size_t)NB * P_TOT * 8);
  // ghist (16 x 65536 u32 = 4 MB) aliases colsupp (2 MB): ghist's lifetime ends
  // at scatter (dispatch 5); colsupp is first written by iou (dispatch 8).
  char* shared_scratch = carve((size_t)NB * 65536 * 4);
  unsigned* ghist = (unsigned*)shared_scratch;
  unsigned long long* colsupp = (unsigned long long*)shared_scratch;
  unsigned* dsel_arr = (unsigned*)carve(NB * 4);
  unsigned long long* stage = (unsigned long long*)carve((size_t)NB * 2048 * 8);
  unsigned long long* topkeys = (unsigned long long*)carve((size_t)NB * PRE_K * 8);
  float* tboxes  = (float*)carve((size_t)NB * PRE_K * 16);
  float* tscores = (float*)carve((size_t)NB * PRE_K * 4);
  int* tlabels   = (int*)carve((size_t)NB * PRE_K * 4);
  unsigned long long* keepmask = (unsigned long long*)carve((size_t)NB * 16 * 8);

  const float* cls0 = (const float*)d_in[0];
  const float* reg0 = (const float*)d_in[1];
  const float* ctr0 = (const float*)d_in[2];
  const float* cls1 = (const float*)d_in[3];
  const float* reg1 = (const float*)d_in[4];
  const float* ctr1 = (const float*)d_in[5];
  const float* cls2 = (const float*)d_in[6];
  const float* reg2 = (const float*)d_in[7];
  const float* ctr2 = (const float*)d_in[8];
  const float* cls3 = (const float*)d_in[9];
  const float* reg3 = (const float*)d_in[10];
  const float* ctr3 = (const float*)d_in[11];
  const float* cls4 = (const float*)d_in[12];
  const float* reg4 = (const float*)d_in[13];
  const float* ctr4 = (const float*)d_in[14];

  hipMemsetAsync(ghist, 0, (size_t)NB * 65536 * 4, stream);
  dim3 dg((P4 + 31) / 32, NB);
  decode_kernel<<<dg, 256, 0, stream>>>(cls0, reg0, ctr0, cls1, reg1, ctr1,
                                        cls2, reg2, ctr2, cls3, reg3, ctr3,
                                        cls4, reg4, ctr4,
                                        labels, boxes, keys);
  dim3 gh((P_TOT + 255) / 256, NB);
  hist_kernel<<<gh, 256, 0, stream>>>(keys, ghist);
  selB_kernel<<<NB, 1024, 0, stream>>>(ghist, dsel_arr, stage);
  scatter_kernel<<<gh, 256, 0, stream>>>(keys, ghist, dsel_arr, stage);
  sortD_kernel<<<NB, 1024, 0, stream>>>(stage, topkeys);
  gather_kernel<<<(NB * PRE_K + 255) / 256, 256, 0, stream>>>(topkeys, boxes, labels,
                                                              tboxes, tscores, tlabels);
  dim3 gi(8, 16, NB);
  iou_kernel<<<gi, 128, 0, stream>>>(tboxes, tlabels, colsupp);
  greedy_kernel<<<NB, 64, 0, stream>>>(colsupp, tscores, keepmask);
  finalize_kernel<<<NB, 1024, 0, stream>>>(keepmask, tscores, tboxes, tlabels, (float*)d_out);
}

// Round 8
// 132.996 us; speedup vs baseline: 1.1009x; 1.0968x over previous
//
#include <hip/hip_runtime.h>
#include <stdint.h>

#pragma clang fp contract(off)

#define NB 16
#define NC 80
#define P_TOT 17064
#define P4 (P_TOT / 4)
#define PRE_K 1000
#define POST_K 100

__device__ __forceinline__ float sigmoidf_(float x) {
  return 1.0f / (1.0f + expf(-x));
}

// Decode with the monotonicity trick: score = sqrt(sigmoid(cls)*sigmoid(ctr))
// is strictly monotone in the raw cls logit, so per-location argmax over classes
// == argmax over RAW logits (first-max tie-break preserved), and the max score
// == score(argmax class), computed exactly ONCE per location. 80x fewer
// transcendentals; emitted values bit-identical to the all-class path.
// Layout: each 4-lane quad owns a 4-location group; lane t4 scans 20 classes.
__global__ __launch_bounds__(256) void decode_kernel(
    const float* __restrict__ cls0, const float* __restrict__ reg0, const float* __restrict__ ctr0,
    const float* __restrict__ cls1, const float* __restrict__ reg1, const float* __restrict__ ctr1,
    const float* __restrict__ cls2, const float* __restrict__ reg2, const float* __restrict__ ctr2,
    const float* __restrict__ cls3, const float* __restrict__ reg3, const float* __restrict__ ctr3,
    const float* __restrict__ cls4, const float* __restrict__ reg4, const float* __restrict__ ctr4,
    int* __restrict__ labels, float* __restrict__ boxes,
    unsigned long long* __restrict__ keys)
{
  int quad = blockIdx.x * 64 + (threadIdx.x >> 2);
  int t4 = threadIdx.x & 3;
  int n = blockIdx.y;
  if (quad >= P4) return;
  int p0 = quad * 4;
  int off, wsh, hw; float stride; const float *cls, *reg, *ctr;
  if (p0 < 12800)      { off = 0;     wsh = 7; hw = 12800; stride = 8.f;   cls = cls0; reg = reg0; ctr = ctr0; }
  else if (p0 < 16000) { off = 12800; wsh = 6; hw = 3200;  stride = 16.f;  cls = cls1; reg = reg1; ctr = ctr1; }
  else if (p0 < 16800) { off = 16000; wsh = 5; hw = 800;   stride = 32.f;  cls = cls2; reg = reg2; ctr = ctr2; }
  else if (p0 < 17008) { off = 16800; wsh = 4; hw = 208;   stride = 64.f;  cls = cls3; reg = reg3; ctr = ctr3; }
  else                 { off = 17008; wsh = 3; hw = 56;    stride = 128.f; cls = cls4; reg = reg4; ctr = ctr4; }
  int loc0 = p0 - off;
  int y = loc0 >> wsh;
  int x0 = loc0 & ((1 << wsh) - 1);
  float py = (float)y * stride + 0.5f * stride;

  int c0 = t4 * 20;
  const float* cptr = cls + (size_t)n * NC * hw + (size_t)c0 * hw + loc0;
  float best[4] = { -3.4e38f, -3.4e38f, -3.4e38f, -3.4e38f };
  int bl[4] = { c0, c0, c0, c0 };
  #pragma unroll
  for (int k = 0; k < 20; ++k) {
    float4 cv = *reinterpret_cast<const float4*>(cptr + (size_t)k * hw);
    int c = c0 + k;
    if (cv.x > best[0]) { best[0] = cv.x; bl[0] = c; }
    if (cv.y > best[1]) { best[1] = cv.y; bl[1] = c; }
    if (cv.z > best[2]) { best[2] = cv.z; bl[2] = c; }
    if (cv.w > best[3]) { best[3] = cv.w; bl[3] = c; }
  }

  // reduce raw-logit max across the quad: tie -> lower label (first-max)
  #pragma unroll
  for (int e = 0; e < 4; ++e) {
    #pragma unroll
    for (int d = 1; d <= 2; d <<= 1) {
      float ob = __shfl_xor(best[e], d);
      int ol = __shfl_xor(bl[e], d);
      if (ob > best[e] || (ob == best[e] && ol < bl[e])) { best[e] = ob; bl[e] = ol; }
    }
  }
  if (t4 != 0) return;

  float4 c4 = *reinterpret_cast<const float4*>(ctr + (size_t)n * hw + loc0);
  float sctr[4] = { sigmoidf_(c4.x), sigmoidf_(c4.y), sigmoidf_(c4.z), sigmoidf_(c4.w) };

  const float* rbase = reg + (size_t)n * 4 * hw + loc0;
  float4 rl = *reinterpret_cast<const float4*>(rbase);
  float4 rt = *reinterpret_cast<const float4*>(rbase + (size_t)hw);
  float4 rr = *reinterpret_cast<const float4*>(rbase + (size_t)2 * hw);
  float4 rb = *reinterpret_cast<const float4*>(rbase + (size_t)3 * hw);
  float dl[4] = { rl.x, rl.y, rl.z, rl.w };
  float dt[4] = { rt.x, rt.y, rt.z, rt.w };
  float dr[4] = { rr.x, rr.y, rr.z, rr.w };
  float db[4] = { rb.x, rb.y, rb.z, rb.w };

  size_t o0 = (size_t)n * P_TOT + p0;
  int4 bl4; int* blp = &bl4.x;
  unsigned long long kk[4];
  #pragma unroll
  for (int e = 0; e < 4; ++e) {
    // exact score for the winning class only (identical arithmetic to reference)
    float s = sqrtf(sigmoidf_(best[e]) * sctr[e]);
    float val = (s > 0.05f) ? s : 0.0f;
    float px = (float)(x0 + e) * stride + 0.5f * stride;
    float x1 = fminf(fmaxf(px - dl[e], 0.f), 1024.f);
    float y1 = fminf(fmaxf(py - dt[e], 0.f), 800.f);
    float x2 = fminf(fmaxf(px + dr[e], 0.f), 1024.f);
    float y2 = fminf(fmaxf(py + db[e], 0.f), 800.f);
    blp[e] = bl[e];
    *reinterpret_cast<float4*>(boxes + 4 * (o0 + e)) = make_float4(x1, y1, x2, y2);
    kk[e] = ((unsigned long long)__float_as_uint(val) << 32)
          | (unsigned long long)(0xFFFFFFFFu - (unsigned)(p0 + e));
  }
  *reinterpret_cast<int4*>(labels + o0) = bl4;
  ulonglong2 k01; k01.x = kk[0]; k01.y = kk[1];
  ulonglong2 k23; k23.x = kk[2]; k23.y = kk[3];
  *reinterpret_cast<ulonglong2*>(keys + o0) = k01;
  *reinterpret_cast<ulonglong2*>(keys + o0 + 2) = k23;
}

// Parallel histogram of key top-16 bits into ghist[n][65536] (pre-zeroed).
__global__ __launch_bounds__(256) void hist_kernel(
    const unsigned long long* __restrict__ keys, unsigned* __restrict__ ghist)
{
  int p = blockIdx.x * 256 + threadIdx.x;
  int n = blockIdx.y;
  if (p >= P_TOT) return;
  unsigned long long k = keys[(size_t)n * P_TOT + p];
  atomicAdd(&ghist[((size_t)n << 16) + (unsigned)(k >> 48)], 1u);
}

// Phase B (per batch): find threshold digit dsel (smallest top-16 value with
// suffix count >= 1000). Then overwrite ghist[h] with the BASE offset (count of
// keys in bins > h) for non-empty bins h >= dsel (all bases < 1000 by
// construction), and zero the 2048-slot staging buffer.
__global__ __launch_bounds__(1024) void selB_kernel(
    unsigned* __restrict__ ghist, unsigned* __restrict__ dsel_arr,
    unsigned long long* __restrict__ stage)
{
  int n = blockIdx.x;
  int tid = threadIdx.x;
  __shared__ unsigned A[1024];
  __shared__ unsigned s_d;

  unsigned* gh = ghist + ((size_t)n << 16);
  unsigned bvs[64];
  const uint4* gh4 = reinterpret_cast<const uint4*>(gh) + (size_t)tid * 16;
  unsigned ssum = 0;
  #pragma unroll
  for (int q = 0; q < 16; ++q) {
    uint4 v = gh4[q];
    bvs[4*q+0] = v.x; bvs[4*q+1] = v.y; bvs[4*q+2] = v.z; bvs[4*q+3] = v.w;
    ssum += v.x + v.y + v.z + v.w;
  }
  A[tid] = ssum;
  __syncthreads();
  // block suffix-scan: A[t] = sum strips t..1023
  for (int ofs = 1; ofs < 1024; ofs <<= 1) {
    unsigned v = A[tid];
    if (tid + ofs < 1024) v += A[tid + ofs];
    __syncthreads();
    A[tid] = v;
    __syncthreads();
  }
  unsigned An = (tid < 1023) ? A[tid + 1] : 0u;
  {
    unsigned At = A[tid];
    if (At >= PRE_K && An < PRE_K) {   // unique crossing strip (A monotone)
      unsigned cum = An;
      int d = tid * 64;
      bool done = false;
      #pragma unroll
      for (int b = 63; b >= 0; --b) {
        if (!done) {
          cum += bvs[b];
          if (cum >= PRE_K) { d = tid * 64 + b; done = true; }
        }
      }
      s_d = (unsigned)d;
      dsel_arr[n] = (unsigned)d;
    }
  }
  __syncthreads();
  unsigned dsel = s_d;
  // write bases for non-empty bins >= dsel (bases < 1000, fit low 16 bits)
  {
    unsigned cum = An;
    #pragma unroll
    for (int b = 63; b >= 0; --b) {
      unsigned h = (unsigned)(tid * 64 + b);
      if (h >= dsel && bvs[b] != 0u) gh[h] = cum;
      cum += bvs[b];
    }
  }
  // zero staging slots
  stage[(size_t)n * 2048 + tid] = 0ULL;
  stage[(size_t)n * 2048 + tid + 1024] = 0ULL;
}

// Phase C: parallel bucket scatter. Each candidate key (top16 >= dsel) takes
// slot = base[h] + within-bin-count (atomic). Slots unique, bin-ordered.
__global__ __launch_bounds__(256) void scatter_kernel(
    const unsigned long long* __restrict__ keys, unsigned* __restrict__ ghist,
    const unsigned* __restrict__ dsel_arr, unsigned long long* __restrict__ stage)
{
  int p = blockIdx.x * 256 + threadIdx.x;
  int n = blockIdx.y;
  if (p >= P_TOT) return;
  unsigned long long k = keys[(size_t)n * P_TOT + p];
  unsigned h = (unsigned)(k >> 48);
  if (h < dsel_arr[n]) return;
  unsigned old = atomicAdd(&ghist[((size_t)n << 16) + h], 0x10000u);
  unsigned slot = (old & 0xFFFFu) + (old >> 16);
  if (slot < 2048) stage[(size_t)n * 2048 + slot] = k;
}

// Phase D (per batch): bitonic-sort the 2048 staged keys desc (zeros pad the
// tail), emit the first 1000 — exactly the top-1000 keys in desc order.
__global__ __launch_bounds__(1024) void sortD_kernel(
    const unsigned long long* __restrict__ stage, unsigned long long* __restrict__ topkeys)
{
  int n = blockIdx.x;
  int tid = threadIdx.x;
  __shared__ unsigned long long skey[2048];
  skey[tid] = stage[(size_t)n * 2048 + tid];
  skey[tid + 1024] = stage[(size_t)n * 2048 + tid + 1024];
  __syncthreads();
  for (int k2 = 2; k2 <= 2048; k2 <<= 1) {
    for (int j = k2 >> 1; j > 0; j >>= 1) {
      #pragma unroll
      for (int e = 0; e < 2; ++e) {
        int idx = tid + e * 1024;
        int ixj = idx ^ j;
        if (ixj > idx) {
          unsigned long long a = skey[idx], bb = skey[ixj];
          bool sw = ((idx & k2) == 0) ? (a < bb) : (a > bb);
          if (sw) { skey[idx] = bb; skey[ixj] = a; }
        }
      }
      __syncthreads();
    }
  }
  if (tid < PRE_K) topkeys[(size_t)n * PRE_K + tid] = skey[tid];
}

__global__ __launch_bounds__(256) void gather_kernel(
    const unsigned long long* __restrict__ topkeys,
    const float* __restrict__ boxes, const int* __restrict__ labels,
    float* __restrict__ tboxes, float* __restrict__ tscores, int* __restrict__ tlabels)
{
  int i = blockIdx.x * 256 + threadIdx.x;
  if (i >= NB * PRE_K) return;
  int n = i / PRE_K;
  unsigned long long k = topkeys[i];
  unsigned idx = 0xFFFFFFFFu - (unsigned)(k & 0xFFFFFFFFu);
  float sc = __uint_as_float((unsigned)(k >> 32));
  size_t src = (size_t)n * P_TOT + idx;
  tscores[i] = sc;
  tlabels[i] = labels[src];
  tboxes[4*(size_t)i+0] = boxes[4*src+0];
  tboxes[4*(size_t)i+1] = boxes[4*src+1];
  tboxes[4*(size_t)i+2] = boxes[4*src+2];
  tboxes[4*(size_t)i+3] = boxes[4*src+3];
}

// COLUMN-major suppression, throughput-shaped.
// grid = (8 j-tiles, 16 i-words, NB).  Thread (jb*128+tid) computes the 64-bit
// word w of column j: bit b set iff i=w*64+b < j and IoU(offset boxes) > 0.6.
// No label test needed: the +label*4096 offset guarantees different-label pairs
// have zero intersection (coords < 4096/2).
__global__ __launch_bounds__(128) void iou_kernel(
    const float* __restrict__ tboxes, const int* __restrict__ tlabels,
    unsigned long long* __restrict__ colsupp)
{
  int jb = blockIdx.x, w = blockIdx.y, n = blockIdx.z;
  int tid = threadIdx.x;
  int j = jb * 128 + tid;
  bool jvalid = (j < PRE_K);

  if (w * 64 >= jb * 128 + 128) {
    if (jvalid) colsupp[((size_t)n * PRE_K + j) * 16 + w] = 0ULL;
    return;
  }

  __shared__ float4 sb[64];
  if (tid < 64) {
    int i = w * 64 + tid;
    float4 v = make_float4(0.f, 0.f, 0.f, 0.f);
    if (i < PRE_K) {
      const float* b = tboxes + ((size_t)n * PRE_K + i) * 4;
      float offv = (float)tlabels[(size_t)n * PRE_K + i] * 4096.0f;
      v = make_float4(b[0] + offv, b[1] + offv, b[2] + offv, b[3] + offv);
    }
    sb[tid] = v;
  }
  __syncthreads();

  float4 bj = make_float4(0.f, 0.f, 0.f, 0.f);
  if (jvalid) {
    const float* b = tboxes + ((size_t)n * PRE_K + j) * 4;
    float offv = (float)tlabels[(size_t)n * PRE_K + j] * 4096.0f;
    bj = make_float4(b[0] + offv, b[1] + offv, b[2] + offv, b[3] + offv);
  }
  float aj = (bj.z - bj.x) * (bj.w - bj.y);

  unsigned long long m = 0;
  int ibase = w * 64;
  #pragma unroll
  for (int b = 0; b < 64; ++b) {
    float4 bi = sb[b];
    float ai = (bi.z - bi.x) * (bi.w - bi.y);
    float lx = fmaxf(bi.x, bj.x), ly = fmaxf(bi.y, bj.y);
    float rx = fminf(bi.z, bj.z), ry = fminf(bi.w, bj.w);
    float iw = fmaxf(rx - lx, 0.f), ih = fmaxf(ry - ly, 0.f);
    float inter = iw * ih;
    float iou = inter / (ai + aj - inter + 1e-9f);
    if (iou > 0.6f && (ibase + b) < j) m |= (1ull << b);
  }
  if (jvalid) colsupp[((size_t)n * PRE_K + j) * 16 + w] = m;
}

// One wave per batch. Fixpoint greedy: per 64-chunk, K = candidates; repeat
// { S = K \ suppressed_by(K); kept |= S; K \= suppressed_by(kept) } until S=0.
// Provably equals the sequential greedy scan (cols only contain rows i<j).
// Cross-chunk words loaded per chunk (future words only), applied post-kept.
__global__ __launch_bounds__(64, 1) void greedy_kernel(
    const unsigned long long* __restrict__ colsupp, const float* __restrict__ tscores,
    unsigned long long* __restrict__ keepmask)
{
  int n = blockIdx.x;
  int l = threadIdx.x;
  const unsigned long long* C = colsupp + (size_t)n * PRE_K * 16;
  const float* sc = tscores + (size_t)n * PRE_K;

  unsigned long long diag[16];
  float sval[16];
  #pragma unroll
  for (int k = 0; k < 16; ++k) {
    int j = k * 64 + l;
    diag[k] = (j < PRE_K) ? C[(size_t)j * 16 + k] : 0ULL;
    sval[k] = (j < PRE_K) ? sc[j] : 0.f;
  }

  unsigned removedbits = 0;  // bit k: column k*64+l removed
  #pragma unroll
  for (int c = 0; c < 16; ++c) {
    unsigned long long X[16];
    #pragma unroll
    for (int w = 0; w < 16; ++w) {
      X[w] = 0ULL;
      if (w > c) {
        int j = w * 64 + l;
        if (j < PRE_K) X[w] = C[(size_t)j * 16 + c];
      }
    }
    unsigned long long sp = __ballot(sval[c] > 0.f);
    unsigned long long inc = __ballot(((removedbits >> c) & 1u) != 0u);
    unsigned long long K = sp & ~inc;
    unsigned long long col = diag[c];
    unsigned long long kept = 0;
    for (int it = 0; it < 64; ++it) {
      unsigned long long Bsupp = __ballot((col & K) != 0ULL);
      unsigned long long Snew = K & ~Bsupp & ~kept;
      if (Snew == 0ULL) break;
      kept |= Snew;
      unsigned long long Bd = __ballot((col & kept) != 0ULL);
      K &= ~Bd;
    }
    if ((col & kept) != 0ULL) removedbits |= (1u << c);
    #pragma unroll
    for (int w = 0; w < 16; ++w)
      if (w > c && (X[w] & kept) != 0ULL) removedbits |= (1u << w);
  }
  #pragma unroll
  for (int k = 0; k < 16; ++k) {
    unsigned long long w = __ballot(((removedbits >> k) & 1u) != 0u);
    if (l == 0) keepmask[(size_t)n * 16 + k] = w;
  }
}

__global__ __launch_bounds__(1024) void finalize_kernel(
    const unsigned long long* __restrict__ keepmask, const float* __restrict__ tscores,
    const float* __restrict__ tboxes, const int* __restrict__ tlabels,
    float* __restrict__ out)
{
  int n = blockIdx.x;
  int tid = threadIdx.x;
  __shared__ unsigned sk[1024];
  __shared__ unsigned sz[1024];
  bool inr = (tid < PRE_K);
  bool keep = false; float sc = 0.f;
  if (inr) {
    unsigned long long w = keepmask[(size_t)n * 16 + (tid >> 6)];
    bool rem = (w >> (tid & 63)) & 1ull;
    sc = tscores[(size_t)n * PRE_K + tid];
    keep = (!rem) && (sc > 0.f);
  }
  sk[tid] = keep ? 1u : 0u;
  sz[tid] = (inr && !keep) ? 1u : 0u;
  __syncthreads();
  for (int ofs = 1; ofs < 1024; ofs <<= 1) {
    unsigned a = (tid >= ofs) ? sk[tid - ofs] : 0;
    unsigned b = (tid >= ofs) ? sz[tid - ofs] : 0;
    __syncthreads();
    sk[tid] += a; sz[tid] += b;
    __syncthreads();
  }
  int nk = (int)sk[1023];
  int slot = -1;
  if (inr) {
    if (keep) {
      int r = (int)sk[tid] - 1;
      if (r < POST_K) slot = r;
    } else {
      int r = nk + (int)sz[tid] - 1;
      if (r < POST_K) slot = r;
    }
  }
  if (slot >= 0) {
    size_t src = (size_t)n * PRE_K + tid;
    size_t ob = ((size_t)n * POST_K + slot) * 4;
    out[ob+0] = tboxes[4*src+0];
    out[ob+1] = tboxes[4*src+1];
    out[ob+2] = tboxes[4*src+2];
    out[ob+3] = tboxes[4*src+3];
    out[(size_t)NB*POST_K*4 + (size_t)n*POST_K + slot] = keep ? sc : 0.0f;
    out[(size_t)NB*POST_K*5 + (size_t)n*POST_K + slot] = (float)tlabels[src];
  }
}

extern "C" void kernel_launch(void* const* d_in, const int* in_sizes, int n_in,
                              void* d_out, int out_size, void* d_ws, size_t ws_size,
                              hipStream_t stream) {
  char* w = (char*)d_ws;
  auto carve = [&](size_t bytes) { char* p = w; w += (bytes + 255) & ~(size_t)255; return p; };
  int* labels   = (int*)carve((size_t)NB * P_TOT * 4);
  float* boxes  = (float*)carve((size_t)NB * P_TOT * 16);
  unsigned long long* keys    = (unsigned long long*)carve((size_t)NB * P_TOT * 8);
  // ghist (16 x 65536 u32 = 4 MB) aliases colsupp (2 MB): ghist's lifetime ends
  // at scatter (dispatch 5); colsupp is first written by iou (dispatch 8).
  char* shared_scratch = carve((size_t)NB * 65536 * 4);
  unsigned* ghist = (unsigned*)shared_scratch;
  unsigned long long* colsupp = (unsigned long long*)shared_scratch;
  unsigned* dsel_arr = (unsigned*)carve(NB * 4);
  unsigned long long* stage = (unsigned long long*)carve((size_t)NB * 2048 * 8);
  unsigned long long* topkeys = (unsigned long long*)carve((size_t)NB * PRE_K * 8);
  float* tboxes  = (float*)carve((size_t)NB * PRE_K * 16);
  float* tscores = (float*)carve((size_t)NB * PRE_K * 4);
  int* tlabels   = (int*)carve((size_t)NB * PRE_K * 4);
  unsigned long long* keepmask = (unsigned long long*)carve((size_t)NB * 16 * 8);

  const float* cls0 = (const float*)d_in[0];
  const float* reg0 = (const float*)d_in[1];
  const float* ctr0 = (const float*)d_in[2];
  const float* cls1 = (const float*)d_in[3];
  const float* reg1 = (const float*)d_in[4];
  const float* ctr1 = (const float*)d_in[5];
  const float* cls2 = (const float*)d_in[6];
  const float* reg2 = (const float*)d_in[7];
  const float* ctr2 = (const float*)d_in[8];
  const float* cls3 = (const float*)d_in[9];
  const float* reg3 = (const float*)d_in[10];
  const float* ctr3 = (const float*)d_in[11];
  const float* cls4 = (const float*)d_in[12];
  const float* reg4 = (const float*)d_in[13];
  const float* ctr4 = (const float*)d_in[14];

  hipMemsetAsync(ghist, 0, (size_t)NB * 65536 * 4, stream);
  dim3 dg((P4 + 63) / 64, NB);
  decode_kernel<<<dg, 256, 0, stream>>>(cls0, reg0, ctr0, cls1, reg1, ctr1,
                                        cls2, reg2, ctr2, cls3, reg3, ctr3,
                                        cls4, reg4, ctr4,
                                        labels, boxes, keys);
  dim3 gh((P_TOT + 255) / 256, NB);
  hist_kernel<<<gh, 256, 0, stream>>>(keys, ghist);
  selB_kernel<<<NB, 1024, 0, stream>>>(ghist, dsel_arr, stage);
  scatter_kernel<<<gh, 256, 0, stream>>>(keys, ghist, dsel_arr, stage);
  sortD_kernel<<<NB, 1024, 0, stream>>>(stage, topkeys);
  gather_kernel<<<(NB * PRE_K + 255) / 256, 256, 0, stream>>>(topkeys, boxes, labels,
                                                              tboxes, tscores, tlabels);
  dim3 gi(8, 16, NB);
  iou_kernel<<<gi, 128, 0, stream>>>(tboxes, tlabels, colsupp);
  greedy_kernel<<<NB, 64, 0, stream>>>(colsupp, tscores, keepmask);
  finalize_kernel<<<NB, 1024, 0, stream>>>(keepmask, tscores, tboxes, tlabels, (float*)d_out);
}

// Round 9
// 129.660 us; speedup vs baseline: 1.1292x; 1.0257x over previous
//
#include <hip/hip_runtime.h>
#include <stdint.h>

#pragma clang fp contract(off)

#define NB 16
#define NC 80
#define P_TOT 17064
#define P4 (P_TOT / 4)
#define PRE_K 1000
#define POST_K 100

__device__ __forceinline__ float sigmoidf_(float x) {
  return 1.0f / (1.0f + expf(-x));
}

// Fast zero of ghist (replaces 40us rocclr fillBuffer with a full-grid kernel).
__global__ __launch_bounds__(256) void zero_kernel(uint4* __restrict__ p, int n4) {
  int i = blockIdx.x * 256 + threadIdx.x;
  if (i < n4) p[i] = make_uint4(0u, 0u, 0u, 0u);
}

// Decode with the monotonicity trick: score = sqrt(sigmoid(cls)*sigmoid(ctr))
// is strictly monotone in the raw cls logit, so per-location argmax over classes
// == argmax over RAW logits (first-max tie-break preserved), and the max score
// == score(argmax class), computed exactly ONCE per location.
__global__ __launch_bounds__(256) void decode_kernel(
    const float* __restrict__ cls0, const float* __restrict__ reg0, const float* __restrict__ ctr0,
    const float* __restrict__ cls1, const float* __restrict__ reg1, const float* __restrict__ ctr1,
    const float* __restrict__ cls2, const float* __restrict__ reg2, const float* __restrict__ ctr2,
    const float* __restrict__ cls3, const float* __restrict__ reg3, const float* __restrict__ ctr3,
    const float* __restrict__ cls4, const float* __restrict__ reg4, const float* __restrict__ ctr4,
    int* __restrict__ labels, float* __restrict__ boxes,
    unsigned long long* __restrict__ keys)
{
  int quad = blockIdx.x * 64 + (threadIdx.x >> 2);
  int t4 = threadIdx.x & 3;
  int n = blockIdx.y;
  if (quad >= P4) return;
  int p0 = quad * 4;
  int off, wsh, hw; float stride; const float *cls, *reg, *ctr;
  if (p0 < 12800)      { off = 0;     wsh = 7; hw = 12800; stride = 8.f;   cls = cls0; reg = reg0; ctr = ctr0; }
  else if (p0 < 16000) { off = 12800; wsh = 6; hw = 3200;  stride = 16.f;  cls = cls1; reg = reg1; ctr = ctr1; }
  else if (p0 < 16800) { off = 16000; wsh = 5; hw = 800;   stride = 32.f;  cls = cls2; reg = reg2; ctr = ctr2; }
  else if (p0 < 17008) { off = 16800; wsh = 4; hw = 208;   stride = 64.f;  cls = cls3; reg = reg3; ctr = ctr3; }
  else                 { off = 17008; wsh = 3; hw = 56;    stride = 128.f; cls = cls4; reg = reg4; ctr = ctr4; }
  int loc0 = p0 - off;
  int y = loc0 >> wsh;
  int x0 = loc0 & ((1 << wsh) - 1);
  float py = (float)y * stride + 0.5f * stride;

  int c0 = t4 * 20;
  const float* cptr = cls + (size_t)n * NC * hw + (size_t)c0 * hw + loc0;
  float best[4] = { -3.4e38f, -3.4e38f, -3.4e38f, -3.4e38f };
  int bl[4] = { c0, c0, c0, c0 };
  #pragma unroll
  for (int k = 0; k < 20; ++k) {
    float4 cv = *reinterpret_cast<const float4*>(cptr + (size_t)k * hw);
    int c = c0 + k;
    if (cv.x > best[0]) { best[0] = cv.x; bl[0] = c; }
    if (cv.y > best[1]) { best[1] = cv.y; bl[1] = c; }
    if (cv.z > best[2]) { best[2] = cv.z; bl[2] = c; }
    if (cv.w > best[3]) { best[3] = cv.w; bl[3] = c; }
  }

  // reduce raw-logit max across the quad: tie -> lower label (first-max)
  #pragma unroll
  for (int e = 0; e < 4; ++e) {
    #pragma unroll
    for (int d = 1; d <= 2; d <<= 1) {
      float ob = __shfl_xor(best[e], d);
      int ol = __shfl_xor(bl[e], d);
      if (ob > best[e] || (ob == best[e] && ol < bl[e])) { best[e] = ob; bl[e] = ol; }
    }
  }
  if (t4 != 0) return;

  float4 c4 = *reinterpret_cast<const float4*>(ctr + (size_t)n * hw + loc0);
  float sctr[4] = { sigmoidf_(c4.x), sigmoidf_(c4.y), sigmoidf_(c4.z), sigmoidf_(c4.w) };

  const float* rbase = reg + (size_t)n * 4 * hw + loc0;
  float4 rl = *reinterpret_cast<const float4*>(rbase);
  float4 rt = *reinterpret_cast<const float4*>(rbase + (size_t)hw);
  float4 rr = *reinterpret_cast<const float4*>(rbase + (size_t)2 * hw);
  float4 rb = *reinterpret_cast<const float4*>(rbase + (size_t)3 * hw);
  float dl[4] = { rl.x, rl.y, rl.z, rl.w };
  float dt[4] = { rt.x, rt.y, rt.z, rt.w };
  float dr[4] = { rr.x, rr.y, rr.z, rr.w };
  float db[4] = { rb.x, rb.y, rb.z, rb.w };

  size_t o0 = (size_t)n * P_TOT + p0;
  int4 bl4; int* blp = &bl4.x;
  unsigned long long kk[4];
  #pragma unroll
  for (int e = 0; e < 4; ++e) {
    float s = sqrtf(sigmoidf_(best[e]) * sctr[e]);
    float val = (s > 0.05f) ? s : 0.0f;
    float px = (float)(x0 + e) * stride + 0.5f * stride;
    float x1 = fminf(fmaxf(px - dl[e], 0.f), 1024.f);
    float y1 = fminf(fmaxf(py - dt[e], 0.f), 800.f);
    float x2 = fminf(fmaxf(px + dr[e], 0.f), 1024.f);
    float y2 = fminf(fmaxf(py + db[e], 0.f), 800.f);
    blp[e] = bl[e];
    *reinterpret_cast<float4*>(boxes + 4 * (o0 + e)) = make_float4(x1, y1, x2, y2);
    kk[e] = ((unsigned long long)__float_as_uint(val) << 32)
          | (unsigned long long)(0xFFFFFFFFu - (unsigned)(p0 + e));
  }
  *reinterpret_cast<int4*>(labels + o0) = bl4;
  ulonglong2 k01; k01.x = kk[0]; k01.y = kk[1];
  ulonglong2 k23; k23.x = kk[2]; k23.y = kk[3];
  *reinterpret_cast<ulonglong2*>(keys + o0) = k01;
  *reinterpret_cast<ulonglong2*>(keys + o0 + 2) = k23;
}

// Parallel histogram of key top-16 bits into ghist[n][65536] (pre-zeroed).
__global__ __launch_bounds__(256) void hist_kernel(
    const unsigned long long* __restrict__ keys, unsigned* __restrict__ ghist)
{
  int p = blockIdx.x * 256 + threadIdx.x;
  int n = blockIdx.y;
  if (p >= P_TOT) return;
  unsigned long long k = keys[(size_t)n * P_TOT + p];
  atomicAdd(&ghist[((size_t)n << 16) + (unsigned)(k >> 48)], 1u);
}

// Phase B (per batch): find threshold digit dsel (smallest top-16 value with
// suffix count >= 1000). Then overwrite ghist[h] with the BASE offset (count of
// keys in bins > h) for non-empty bins h >= dsel, zero the staging buffer.
__global__ __launch_bounds__(1024) void selB_kernel(
    unsigned* __restrict__ ghist, unsigned* __restrict__ dsel_arr,
    unsigned long long* __restrict__ stage)
{
  int n = blockIdx.x;
  int tid = threadIdx.x;
  __shared__ unsigned A[1024];
  __shared__ unsigned s_d;

  unsigned* gh = ghist + ((size_t)n << 16);
  unsigned bvs[64];
  const uint4* gh4 = reinterpret_cast<const uint4*>(gh) + (size_t)tid * 16;
  unsigned ssum = 0;
  #pragma unroll
  for (int q = 0; q < 16; ++q) {
    uint4 v = gh4[q];
    bvs[4*q+0] = v.x; bvs[4*q+1] = v.y; bvs[4*q+2] = v.z; bvs[4*q+3] = v.w;
    ssum += v.x + v.y + v.z + v.w;
  }
  A[tid] = ssum;
  __syncthreads();
  for (int ofs = 1; ofs < 1024; ofs <<= 1) {
    unsigned v = A[tid];
    if (tid + ofs < 1024) v += A[tid + ofs];
    __syncthreads();
    A[tid] = v;
    __syncthreads();
  }
  unsigned An = (tid < 1023) ? A[tid + 1] : 0u;
  {
    unsigned At = A[tid];
    if (At >= PRE_K && An < PRE_K) {
      unsigned cum = An;
      int d = tid * 64;
      bool done = false;
      #pragma unroll
      for (int b = 63; b >= 0; --b) {
        if (!done) {
          cum += bvs[b];
          if (cum >= PRE_K) { d = tid * 64 + b; done = true; }
        }
      }
      s_d = (unsigned)d;
      dsel_arr[n] = (unsigned)d;
    }
  }
  __syncthreads();
  unsigned dsel = s_d;
  {
    unsigned cum = An;
    #pragma unroll
    for (int b = 63; b >= 0; --b) {
      unsigned h = (unsigned)(tid * 64 + b);
      if (h >= dsel && bvs[b] != 0u) gh[h] = cum;
      cum += bvs[b];
    }
  }
  stage[(size_t)n * 2048 + tid] = 0ULL;
  stage[(size_t)n * 2048 + tid + 1024] = 0ULL;
}

// Phase C: parallel bucket scatter. Each candidate key (top16 >= dsel) takes
// slot = base[h] + within-bin-count (atomic). Slots unique, bin-ordered.
__global__ __launch_bounds__(256) void scatter_kernel(
    const unsigned long long* __restrict__ keys, unsigned* __restrict__ ghist,
    const unsigned* __restrict__ dsel_arr, unsigned long long* __restrict__ stage)
{
  int p = blockIdx.x * 256 + threadIdx.x;
  int n = blockIdx.y;
  if (p >= P_TOT) return;
  unsigned long long k = keys[(size_t)n * P_TOT + p];
  unsigned h = (unsigned)(k >> 48);
  if (h < dsel_arr[n]) return;
  unsigned old = atomicAdd(&ghist[((size_t)n << 16) + h], 0x10000u);
  unsigned slot = (old & 0xFFFFu) + (old >> 16);
  if (slot < 2048) stage[(size_t)n * 2048 + slot] = k;
}

// Phase D (per batch): bitonic-sort the 2048 staged keys desc, emit first 1000.
__global__ __launch_bounds__(1024) void sortD_kernel(
    const unsigned long long* __restrict__ stage, unsigned long long* __restrict__ topkeys)
{
  int n = blockIdx.x;
  int tid = threadIdx.x;
  __shared__ unsigned long long skey[2048];
  skey[tid] = stage[(size_t)n * 2048 + tid];
  skey[tid + 1024] = stage[(size_t)n * 2048 + tid + 1024];
  __syncthreads();
  for (int k2 = 2; k2 <= 2048; k2 <<= 1) {
    for (int j = k2 >> 1; j > 0; j >>= 1) {
      #pragma unroll
      for (int e = 0; e < 2; ++e) {
        int idx = tid + e * 1024;
        int ixj = idx ^ j;
        if (ixj > idx) {
          unsigned long long a = skey[idx], bb = skey[ixj];
          bool sw = ((idx & k2) == 0) ? (a < bb) : (a > bb);
          if (sw) { skey[idx] = bb; skey[ixj] = a; }
        }
      }
      __syncthreads();
    }
  }
  if (tid < PRE_K) topkeys[(size_t)n * PRE_K + tid] = skey[tid];
}

__global__ __launch_bounds__(256) void gather_kernel(
    const unsigned long long* __restrict__ topkeys,
    const float* __restrict__ boxes, const int* __restrict__ labels,
    float* __restrict__ tboxes, float* __restrict__ tscores, int* __restrict__ tlabels)
{
  int i = blockIdx.x * 256 + threadIdx.x;
  if (i >= NB * PRE_K) return;
  int n = i / PRE_K;
  unsigned long long k = topkeys[i];
  unsigned idx = 0xFFFFFFFFu - (unsigned)(k & 0xFFFFFFFFu);
  float sc = __uint_as_float((unsigned)(k >> 32));
  size_t src = (size_t)n * P_TOT + idx;
  tscores[i] = sc;
  tlabels[i] = labels[src];
  tboxes[4*(size_t)i+0] = boxes[4*src+0];
  tboxes[4*(size_t)i+1] = boxes[4*src+1];
  tboxes[4*(size_t)i+2] = boxes[4*src+2];
  tboxes[4*(size_t)i+3] = boxes[4*src+3];
}

// COLUMN-major suppression. Thread (jb*128+tid) computes word w of column j.
// Divide-free: t = inter - 0.6f*denom decides unless |t| <= denom*2^-17
// (guard band covering mul+div rounding), in which case the exact reference
// divide resolves it. Decisions bit-identical to fl(inter/denom) > 0.6f.
__global__ __launch_bounds__(128) void iou_kernel(
    const float* __restrict__ tboxes, const int* __restrict__ tlabels,
    unsigned long long* __restrict__ colsupp)
{
  int jb = blockIdx.x, w = blockIdx.y, n = blockIdx.z;
  int tid = threadIdx.x;
  int j = jb * 128 + tid;
  bool jvalid = (j < PRE_K);
  int ibase = w * 64;

  if (ibase >= jb * 128 + 128) {  // entirely above diagonal
    if (jvalid) colsupp[((size_t)n * PRE_K + j) * 16 + w] = 0ULL;
    return;
  }

  __shared__ float4 sb[64];
  __shared__ float sa[64];
  if (tid < 64) {
    int i = ibase + tid;
    float4 v = make_float4(0.f, 0.f, 0.f, 0.f);
    if (i < PRE_K) {
      const float* b = tboxes + ((size_t)n * PRE_K + i) * 4;
      float offv = (float)tlabels[(size_t)n * PRE_K + i] * 4096.0f;
      v = make_float4(b[0] + offv, b[1] + offv, b[2] + offv, b[3] + offv);
    }
    sb[tid] = v;
    sa[tid] = (v.z - v.x) * (v.w - v.y);
  }
  __syncthreads();

  float4 bj = make_float4(0.f, 0.f, 0.f, 0.f);
  if (jvalid) {
    const float* b = tboxes + ((size_t)n * PRE_K + j) * 4;
    float offv = (float)tlabels[(size_t)n * PRE_K + j] * 4096.0f;
    bj = make_float4(b[0] + offv, b[1] + offv, b[2] + offv, b[3] + offv);
  }
  float aj = (bj.z - bj.x) * (bj.w - bj.y);

  unsigned long long m = 0, mb = 0;
  #pragma unroll
  for (int b = 0; b < 64; ++b) {
    float4 bi = sb[b];
    float ai = sa[b];
    float lx = fmaxf(bi.x, bj.x), ly = fmaxf(bi.y, bj.y);
    float rx = fminf(bi.z, bj.z), ry = fminf(bi.w, bj.w);
    float iw = fmaxf(rx - lx, 0.f), ih = fmaxf(ry - ly, 0.f);
    float inter = iw * ih;
    float denom = ai + aj - inter + 1e-9f;
    float t = inter - 0.6f * denom;
    if (t > 0.f) m |= (1ull << b);
    if (fabsf(t) <= denom * 7.62939453125e-6f) mb |= (1ull << b);  // 2^-17
  }
  if (mb) {  // rare: resolve borderline bits with the exact reference divide
    unsigned long long r = mb;
    while (r) {
      int b = __ffsll(r) - 1; r &= r - 1;
      float4 bi = sb[b];
      float ai = sa[b];
      float lx = fmaxf(bi.x, bj.x), ly = fmaxf(bi.y, bj.y);
      float rx = fminf(bi.z, bj.z), ry = fminf(bi.w, bj.w);
      float iw = fmaxf(rx - lx, 0.f), ih = fmaxf(ry - ly, 0.f);
      float inter = iw * ih;
      float denom = ai + aj - inter + 1e-9f;
      float iou = inter / denom;
      if (iou > 0.6f) m |= (1ull << b); else m &= ~(1ull << b);
    }
  }
  // triangle mask: keep only bits with ibase+b < j
  unsigned long long tri;
  if (ibase >= j) tri = 0ULL;
  else if (j - ibase >= 64) tri = ~0ULL;
  else tri = (1ull << (j - ibase)) - 1ull;
  m &= tri;
  if (jvalid) colsupp[((size_t)n * PRE_K + j) * 16 + w] = m;
}

// One wave per batch. Fixpoint greedy (provably == sequential greedy scan).
__global__ __launch_bounds__(64, 1) void greedy_kernel(
    const unsigned long long* __restrict__ colsupp, const float* __restrict__ tscores,
    unsigned long long* __restrict__ keepmask)
{
  int n = blockIdx.x;
  int l = threadIdx.x;
  const unsigned long long* C = colsupp + (size_t)n * PRE_K * 16;
  const float* sc = tscores + (size_t)n * PRE_K;

  unsigned long long diag[16];
  float sval[16];
  #pragma unroll
  for (int k = 0; k < 16; ++k) {
    int j = k * 64 + l;
    diag[k] = (j < PRE_K) ? C[(size_t)j * 16 + k] : 0ULL;
    sval[k] = (j < PRE_K) ? sc[j] : 0.f;
  }

  unsigned removedbits = 0;
  #pragma unroll
  for (int c = 0; c < 16; ++c) {
    unsigned long long X[16];
    #pragma unroll
    for (int w = 0; w < 16; ++w) {
      X[w] = 0ULL;
      if (w > c) {
        int j = w * 64 + l;
        if (j < PRE_K) X[w] = C[(size_t)j * 16 + c];
      }
    }
    unsigned long long sp = __ballot(sval[c] > 0.f);
    unsigned long long inc = __ballot(((removedbits >> c) & 1u) != 0u);
    unsigned long long K = sp & ~inc;
    unsigned long long col = diag[c];
    unsigned long long kept = 0;
    for (int it = 0; it < 64; ++it) {
      unsigned long long Bsupp = __ballot((col & K) != 0ULL);
      unsigned long long Snew = K & ~Bsupp & ~kept;
      if (Snew == 0ULL) break;
      kept |= Snew;
      unsigned long long Bd = __ballot((col & kept) != 0ULL);
      K &= ~Bd;
    }
    if ((col & kept) != 0ULL) removedbits |= (1u << c);
    #pragma unroll
    for (int w = 0; w < 16; ++w)
      if (w > c && (X[w] & kept) != 0ULL) removedbits |= (1u << w);
  }
  #pragma unroll
  for (int k = 0; k < 16; ++k) {
    unsigned long long w = __ballot(((removedbits >> k) & 1u) != 0u);
    if (l == 0) keepmask[(size_t)n * 16 + k] = w;
  }
}

__global__ __launch_bounds__(1024) void finalize_kernel(
    const unsigned long long* __restrict__ keepmask, const float* __restrict__ tscores,
    const float* __restrict__ tboxes, const int* __restrict__ tlabels,
    float* __restrict__ out)
{
  int n = blockIdx.x;
  int tid = threadIdx.x;
  __shared__ unsigned sk[1024];
  __shared__ unsigned sz[1024];
  bool inr = (tid < PRE_K);
  bool keep = false; float sc = 0.f;
  if (inr) {
    unsigned long long w = keepmask[(size_t)n * 16 + (tid >> 6)];
    bool rem = (w >> (tid & 63)) & 1ull;
    sc = tscores[(size_t)n * PRE_K + tid];
    keep = (!rem) && (sc > 0.f);
  }
  sk[tid] = keep ? 1u : 0u;
  sz[tid] = (inr && !keep) ? 1u : 0u;
  __syncthreads();
  for (int ofs = 1; ofs < 1024; ofs <<= 1) {
    unsigned a = (tid >= ofs) ? sk[tid - ofs] : 0;
    unsigned b = (tid >= ofs) ? sz[tid - ofs] : 0;
    __syncthreads();
    sk[tid] += a; sz[tid] += b;
    __syncthreads();
  }
  int nk = (int)sk[1023];
  int slot = -1;
  if (inr) {
    if (keep) {
      int r = (int)sk[tid] - 1;
      if (r < POST_K) slot = r;
    } else {
      int r = nk + (int)sz[tid] - 1;
      if (r < POST_K) slot = r;
    }
  }
  if (slot >= 0) {
    size_t src = (size_t)n * PRE_K + tid;
    size_t ob = ((size_t)n * POST_K + slot) * 4;
    out[ob+0] = tboxes[4*src+0];
    out[ob+1] = tboxes[4*src+1];
    out[ob+2] = tboxes[4*src+2];
    out[ob+3] = tboxes[4*src+3];
    out[(size_t)NB*POST_K*4 + (size_t)n*POST_K + slot] = keep ? sc : 0.0f;
    out[(size_t)NB*POST_K*5 + (size_t)n*POST_K + slot] = (float)tlabels[src];
  }
}

extern "C" void kernel_launch(void* const* d_in, const int* in_sizes, int n_in,
                              void* d_out, int out_size, void* d_ws, size_t ws_size,
                              hipStream_t stream) {
  char* w = (char*)d_ws;
  auto carve = [&](size_t bytes) { char* p = w; w += (bytes + 255) & ~(size_t)255; return p; };
  int* labels   = (int*)carve((size_t)NB * P_TOT * 4);
  float* boxes  = (float*)carve((size_t)NB * P_TOT * 16);
  unsigned long long* keys    = (unsigned long long*)carve((size_t)NB * P_TOT * 8);
  // ghist (4 MB) aliases colsupp (2 MB): ghist dead after scatter; colsupp
  // first written by iou (later dispatch).
  char* shared_scratch = carve((size_t)NB * 65536 * 4);
  unsigned* ghist = (unsigned*)shared_scratch;
  unsigned long long* colsupp = (unsigned long long*)shared_scratch;
  unsigned* dsel_arr = (unsigned*)carve(NB * 4);
  unsigned long long* stage = (unsigned long long*)carve((size_t)NB * 2048 * 8);
  unsigned long long* topkeys = (unsigned long long*)carve((size_t)NB * PRE_K * 8);
  float* tboxes  = (float*)carve((size_t)NB * PRE_K * 16);
  float* tscores = (float*)carve((size_t)NB * PRE_K * 4);
  int* tlabels   = (int*)carve((size_t)NB * PRE_K * 4);
  unsigned long long* keepmask = (unsigned long long*)carve((size_t)NB * 16 * 8);

  const float* cls0 = (const float*)d_in[0];
  const float* reg0 = (const float*)d_in[1];
  const float* ctr0 = (const float*)d_in[2];
  const float* cls1 = (const float*)d_in[3];
  const float* reg1 = (const float*)d_in[4];
  const float* ctr1 = (const float*)d_in[5];
  const float* cls2 = (const float*)d_in[6];
  const float* reg2 = (const float*)d_in[7];
  const float* ctr2 = (const float*)d_in[8];
  const float* cls3 = (const float*)d_in[9];
  const float* reg3 = (const float*)d_in[10];
  const float* ctr3 = (const float*)d_in[11];
  const float* cls4 = (const float*)d_in[12];
  const float* reg4 = (const float*)d_in[13];
  const float* ctr4 = (const float*)d_in[14];

  int n4 = NB * 65536 / 4;  // uint4 count for 4 MB
  zero_kernel<<<(n4 + 255) / 256, 256, 0, stream>>>((uint4*)ghist, n4);
  dim3 dg((P4 + 63) / 64, NB);
  decode_kernel<<<dg, 256, 0, stream>>>(cls0, reg0, ctr0, cls1, reg1, ctr1,
                                        cls2, reg2, ctr2, cls3, reg3, ctr3,
                                        cls4, reg4, ctr4,
                                        labels, boxes, keys);
  dim3 gh((P_TOT + 255) / 256, NB);
  hist_kernel<<<gh, 256, 0, stream>>>(keys, ghist);
  selB_kernel<<<NB, 1024, 0, stream>>>(ghist, dsel_arr, stage);
  scatter_kernel<<<gh, 256, 0, stream>>>(keys, ghist, dsel_arr, stage);
  sortD_kernel<<<NB, 1024, 0, stream>>>(stage, topkeys);
  gather_kernel<<<(NB * PRE_K + 255) / 256, 256, 0, stream>>>(topkeys, boxes, labels,
                                                              tboxes, tscores, tlabels);
  dim3 gi(8, 16, NB);
  iou_kernel<<<gi, 128, 0, stream>>>(tboxes, tlabels, colsupp);
  greedy_kernel<<<NB, 64, 0, stream>>>(colsupp, tscores, keepmask);
  finalize_kernel<<<NB, 1024, 0, stream>>>(keepmask, tscores, tboxes, tlabels, (float*)d_out);
}